// Round 4
// baseline (51.801 us; speedup 1.0000x reference)
//
#include <hip/hip_runtime.h>

// Reference: x (16,1,128,128) f32; out (16,1,2048,2048) f32.
// out[0,0] = nearest-neighbor 16x16 upsample of x[0,0]; rest zero.
// Single kernel, grid-stride, nontemporal float4 streaming stores.

#define OUT_W 2048
#define SRC_W 128
#define IMG0_F4 (2048 * 2048 / 4)        // 1,048,576 float4 in image 0
#define N4_TOTAL (16 * 2048 * 2048 / 4)  // 16,777,216 float4 total

typedef float f4 __attribute__((ext_vector_type(4)));  // native vector: nontemporal-OK

__global__ void fill_all(const float* __restrict__ x, f4* __restrict__ out) {
    const int stride = gridDim.x * blockDim.x;           // 2,097,152
    int tid = blockIdx.x * blockDim.x + threadIdx.x;
    #pragma unroll
    for (int i = 0; i < N4_TOTAL / (8192 * 256); ++i) {  // 8 iterations
        f4 v4 = (f4)(0.f);
        if (tid < IMG0_F4) {
            int e = tid << 2;                  // element index in image 0
            int r = e >> 11;                   // row (2048 = 2^11)
            int c = e & (OUT_W - 1);           // col, 4-aligned
            // 4-aligned float4 never crosses a 16-element cell boundary.
            float v = x[(r >> 4) * SRC_W + (c >> 4)];
            v4 = (f4)(v);
        }
        __builtin_nontemporal_store(v4, &out[tid]);
        tid += stride;
    }
}

extern "C" void kernel_launch(void* const* d_in, const int* in_sizes, int n_in,
                              void* d_out, int out_size, void* d_ws, size_t ws_size,
                              hipStream_t stream) {
    const float* x = (const float*)d_in[0];
    f4* out = (f4*)d_out;
    fill_all<<<8192, 256, 0, stream>>>(x, out);
}

// Round 5
// 38.993 us; speedup vs baseline: 1.3285x; 1.3285x over previous
//
#include <hip/hip_runtime.h>

// Reference: x (16,1,128,128) f32; out (16,1,2048,2048) f32.
// out[0,0] = nearest-neighbor 16x16 upsample of x[0,0]; rest zero.
// Single fused kernel: every thread stores one float4 of the 256 MB output.
// NOTE (R4 post-mortem): grid-stride + __builtin_nontemporal_store REGRESSED
// to 51.8 us (nt bypasses L2 write-combining; rocclr's 7 TB/s fill uses
// ordinary stores). This flat one-store-per-thread form measured 39.2 us
// = ~256MB / 7 TB/s + launch overhead = practical fill ceiling.

#define OUT_W 2048
#define SRC_W 128
#define IMG0_F4 (2048 * 2048 / 4)   // 1,048,576 float4 in image 0

__global__ void fill_all(const float* __restrict__ x, float4* __restrict__ out) {
    int tid = blockIdx.x * blockDim.x + threadIdx.x;  // 0 .. 16,777,215
    float4 v4 = make_float4(0.f, 0.f, 0.f, 0.f);
    if (tid < IMG0_F4) {
        int e = tid << 2;                  // element index in image 0
        int r = e >> 11;                   // row (2048 = 2^11)
        int c = e & (OUT_W - 1);           // col, 4-aligned
        // 4-aligned float4 never crosses a 16-element upsample cell boundary,
        // so one source element covers the whole float4.
        float v = x[(r >> 4) * SRC_W + (c >> 4)];
        v4 = make_float4(v, v, v, v);
    }
    out[tid] = v4;
}

extern "C" void kernel_launch(void* const* d_in, const int* in_sizes, int n_in,
                              void* d_out, int out_size, void* d_ws, size_t ws_size,
                              hipStream_t stream) {
    const float* x = (const float*)d_in[0];
    float4* out = (float4*)d_out;

    const int n4 = out_size / 4;           // 16,777,216 float4 stores
    fill_all<<<n4 / 256, 256, 0, stream>>>(x, out);
}